// Round 10
// baseline (278.181 us; speedup 1.0000x reference)
//
#include <hip/hip_runtime.h>

typedef unsigned short u16;
typedef __attribute__((ext_vector_type(8))) __bf16 bf16x8;
typedef __attribute__((ext_vector_type(4))) float f32x4;
typedef __attribute__((ext_vector_type(4))) unsigned short u16x4;

#define AS1 __attribute__((address_space(1)))
#define AS3 __attribute__((address_space(3)))

// blob layout (u16 element offsets) -- bf16 copies of x,h ONLY (weights are
// converted inside the fused kernel: each W row-block is read by exactly one
// j-block, so in-kernel conversion duplicates nothing).
#define OB_X    0L
#define OB_H    4194304L
#define BLOB_EL 8388608L

__device__ __forceinline__ u16 f2b(float f) {
    unsigned u = __float_as_uint(f);
    u += 0x7fffu + ((u >> 16) & 1u);   // round-to-nearest-even
    return (u16)(u >> 16);
}

// ---------------- f32 -> bf16 blob build: x,h only (50 MB traffic, was 107) --
__global__ __launch_bounds__(256) void convert_xh(
    const float* __restrict__ x, const float* __restrict__ h,
    u16* __restrict__ blob)
{
    long e = ((long)blockIdx.x * 256 + threadIdx.x) * 8;
    const float* src = (e < OB_H) ? x : h;
    long off = (e < OB_H) ? e : (e - OB_H);
    f32x4 v0 = *(const f32x4*)(src + off);
    f32x4 v1 = *(const f32x4*)(src + off + 4);
    u16x4 o0, o1;
    o0.x = f2b(v0.x); o0.y = f2b(v0.y); o0.z = f2b(v0.z); o0.w = f2b(v0.w);
    o1.x = f2b(v1.x); o1.y = f2b(v1.y); o1.z = f2b(v1.z); o1.w = f2b(v1.w);
    *(u16x4*)(blob + e) = o0;
    *(u16x4*)(blob + e + 4) = o1;
}

__device__ __forceinline__ float sigf(float z) {
    return 1.f / (1.f + __expf(-z));
}

// ---------------- fully-fused SRU-LSTM cell, in-kernel weight conversion ----
// r7 shell verbatim (8 waves, 128m x 64j x 5seg, per-wave 32x32, acc 80,
// single-buffer LDS + 2x __syncthreads -- the structure that benched clean:
// VGPR 60, WRITE 32.77MB, no spill). ONE change: B-tiles come from f32 weights
// via reg-staging (T14 issue-early/write-late: next tile's 10 f32x4 loads are
// issued right after the first barrier, land during compute, cvt+ds_write at
// top of next iter). A-tiles stay on global_load_lds from the small x,h blob.
// Write-side swizzle == old source-side swizzle: LDS[er][g]=global[er][g^key]
// in both, so the r7-verified read side is untouched.
__global__ __launch_bounds__(512) void srulstm_fused(
    const u16* __restrict__ blob,
    const float* __restrict__ Wi, const float* __restrict__ Wf,
    const float* __restrict__ Wo, const float* __restrict__ Wxs,
    const float* __restrict__ Wxg, const float* __restrict__ Whg,
    const float* __restrict__ c_prev,
    const float* __restrict__ bi, const float* __restrict__ bfv,
    const float* __restrict__ bo, const float* __restrict__ bxs,
    const float* __restrict__ bxg, const float* __restrict__ bhg,
    float* __restrict__ out)
{
    __shared__ __align__(16) u16 As[128 * 64];       // 16 KB
    __shared__ __align__(16) u16 Bs[5 * 64 * 64];    // 40 KB

    const u16* x = blob + OB_X;
    const u16* h = blob + OB_H;

    const int t = threadIdx.x;
    const int j0 = blockIdx.x * 64;    // 16 j-slices
    const int m0 = blockIdx.y * 128;   // 32 m-tiles

    const u16* aLo = x + m0 * 1024;
    const u16* aHi = h + m0 * 1024;

    const int lane = t & 63;
    const int wave = t >> 6;           // 0..7
    const int wm = (wave >> 1) << 5;   // 0/32/64/96
    const int wn = (wave & 1) << 5;    // 0/32
    const int fr = lane & 15;
    const int fq = lane >> 4;
    const int r7 = fr & 7;

    const int er = t >> 3;             // staging row (0..63)
    const int g8 = t & 7;              // staging granule (8 elems)
    const int gsw = ((g8 ^ (er & 7)) << 3);   // swizzled LDS granule offset

    // per-thread W source bases: row j0+er, cols g8*8..+7 (+k offset later)
    const float* pWi  = Wi  + (j0 + er) * 2048 + g8 * 8;
    const float* pWf  = Wf  + (j0 + er) * 2048 + g8 * 8;
    const float* pWo  = Wo  + (j0 + er) * 2048 + g8 * 8;
    const float* pWxg = Wxg + (j0 + er) * 1024 + g8 * 8;
    const float* pWhg = Whg + (j0 + er) * 1024 + g8 * 8;
    const float* pWxs = Wxs + (j0 + er) * 1024 + g8 * 8;

    f32x4 acc[5][2][2] = {};           // [seg][mi][ni] -- 80 f32/thread
    f32x4 rb[5][2];                    // prefetched f32 W granules (40 VGPR)

    // ---- issue the 8/10 f32x4 weight loads for tile kS into rb ----
#define LOADB(kS)                                                          \
    if ((kS) < 2048) {                                                     \
        rb[0][0] = *(const f32x4*)(pWi + (kS));                            \
        rb[0][1] = *(const f32x4*)(pWi + (kS) + 4);                        \
        rb[1][0] = *(const f32x4*)(pWf + (kS));                            \
        rb[1][1] = *(const f32x4*)(pWf + (kS) + 4);                        \
        rb[2][0] = *(const f32x4*)(pWo + (kS));                            \
        rb[2][1] = *(const f32x4*)(pWo + (kS) + 4);                        \
        const float* w3 = ((kS) < 1024) ? (pWxg + (kS)) : (pWhg + ((kS) - 1024)); \
        rb[3][0] = *(const f32x4*)(w3);                                    \
        rb[3][1] = *(const f32x4*)(w3 + 4);                                \
        if ((kS) < 1024) {                                                 \
            rb[4][0] = *(const f32x4*)(pWxs + (kS));                       \
            rb[4][1] = *(const f32x4*)(pWxs + (kS) + 4);                   \
        }                                                                  \
    }

    LOADB(0);

    for (int k0 = 0; k0 < 2048; k0 += 64) {
        // ---- cvt + swizzled ds_write of this tile's B (rb -> Bs) ----
#pragma unroll
        for (int s = 0; s < 5; ++s) {
            if (s == 4 && k0 >= 1024) break;   // seg4 only for k<1024
            bf16x8 w;
            w[0] = (__bf16)rb[s][0].x; w[1] = (__bf16)rb[s][0].y;
            w[2] = (__bf16)rb[s][0].z; w[3] = (__bf16)rb[s][0].w;
            w[4] = (__bf16)rb[s][1].x; w[5] = (__bf16)rb[s][1].y;
            w[6] = (__bf16)rb[s][1].z; w[7] = (__bf16)rb[s][1].w;
            *(bf16x8*)(Bs + s * 4096 + er * 64 + gsw) = w;
        }
        // ---- A tile via global_load_lds (2 x 16B per thread) ----
        const u16* aSrc = ((k0 < 1024) ? aLo : aHi) + (k0 & 1023);
#pragma unroll
        for (int it = 0; it < 2; ++it)
            __builtin_amdgcn_global_load_lds(
                (AS1 void*)(aSrc + (it * 64 + er) * 1024 + gsw),
                (AS3 void*)(As + (it * 512 + t) * 8), 16, 0, 0);
        __syncthreads();
        // ---- T14: issue next tile's W loads; latency hides under compute ----
        LOADB(k0 + 64);
        // ---- compute (r7-verified fragment math, verbatim) ----
#pragma unroll
        for (int kk = 0; kk < 64; kk += 32) {
            const int sw = ((((kk >> 3) + fq) ^ r7) << 3);
            bf16x8 a[2];
#pragma unroll
            for (int mi = 0; mi < 2; ++mi)
                a[mi] = *(const bf16x8*)(As + (wm + mi * 16 + fr) * 64 + sw);
#pragma unroll
            for (int s = 0; s < 4; ++s) {
                bf16x8 b0 = *(const bf16x8*)(Bs + s * 4096 + (wn + fr) * 64 + sw);
                bf16x8 b1 = *(const bf16x8*)(Bs + s * 4096 + (wn + 16 + fr) * 64 + sw);
#pragma unroll
                for (int mi = 0; mi < 2; ++mi) {
                    acc[s][mi][0] = __builtin_amdgcn_mfma_f32_16x16x32_bf16(
                        a[mi], b0, acc[s][mi][0], 0, 0, 0);
                    acc[s][mi][1] = __builtin_amdgcn_mfma_f32_16x16x32_bf16(
                        a[mi], b1, acc[s][mi][1], 0, 0, 0);
                }
            }
            if (k0 < 1024) {           // seg 4 (Wxs) has K=1024
                bf16x8 b0 = *(const bf16x8*)(Bs + 16384 + (wn + fr) * 64 + sw);
                bf16x8 b1 = *(const bf16x8*)(Bs + 16384 + (wn + 16 + fr) * 64 + sw);
#pragma unroll
                for (int mi = 0; mi < 2; ++mi) {
                    acc[4][mi][0] = __builtin_amdgcn_mfma_f32_16x16x32_bf16(
                        a[mi], b0, acc[4][mi][0], 0, 0, 0);
                    acc[4][mi][1] = __builtin_amdgcn_mfma_f32_16x16x32_bf16(
                        a[mi], b1, acc[4][mi][1], 0, 0, 0);
                }
            }
        }
        __syncthreads();   // protects As/Bs overwrite; drains the k0+64 loads
    }                      // (landed during compute -> ~free)

    // ---- in-register LSTM epilogue (r7-verified) ----
    // C/D layout (m89): lane holds D[m=fq*4+r][n=fr]; all 5 segs aligned.
    const int orow = m0 + wm + (fq << 2);
    const int ocol = j0 + wn + fr;
#pragma unroll
    for (int ni = 0; ni < 2; ++ni) {
        const int col = ocol + ni * 16;
        const float bi_v = bi[col],  bf_v = bfv[col], bo_v = bo[col];
        const float bs_v = bxs[col], bg_v = bxg[col], bh_v = bhg[col];
#pragma unroll
        for (int mi = 0; mi < 2; ++mi) {
#pragma unroll
            for (int r = 0; r < 4; ++r) {
                const long idx = (long)(orow + mi * 16 + r) * 1024 + col;
                const float cp = c_prev[idx];
                const float i_t = sigf(acc[0][mi][ni][r] + bi_v);
                const float f_t = sigf(acc[1][mi][ni][r] + bf_v);
                const float o_t = sigf(acc[2][mi][ni][r] + bo_v);
                const float cand = acc[3][mi][ni][r] + bg_v + bh_v;
                const float s_t  = acc[4][mi][ni][r] + bs_v;
                const float g_t = tanhf(s_t * cand);
                const float c_t = f_t * cp + i_t * g_t;
                const float h_t = o_t * tanhf(c_t);
                out[idx] = h_t;                    // h_t
                out[4194304L + idx] = c_t;         // c_t
            }
        }
    }
}

extern "C" void kernel_launch(void* const* d_in, const int* in_sizes, int n_in,
                              void* d_out, int out_size, void* d_ws, size_t ws_size,
                              hipStream_t stream)
{
    u16* blob = (u16*)d_ws;            // 16.8 MB (x,h only)
    float* out = (float*)d_out;

    const long convBlocks = BLOB_EL / 8 / 256;     // 4096

    convert_xh<<<dim3(convBlocks), dim3(256), 0, stream>>>(
        (const float*)d_in[0], (const float*)d_in[1], blob);

    srulstm_fused<<<dim3(16, 32), dim3(512), 0, stream>>>(
        blob,
        (const float*)d_in[3], (const float*)d_in[5], (const float*)d_in[7],
        (const float*)d_in[9], (const float*)d_in[11], (const float*)d_in[13],
        (const float*)d_in[2],
        (const float*)d_in[4], (const float*)d_in[6], (const float*)d_in[8],
        (const float*)d_in[10], (const float*)d_in[12], (const float*)d_in[14],
        out);
}